// Round 6
// baseline (888.644 us; speedup 1.0000x reference)
//
#include <hip/hip_runtime.h>

#define TSEQ 2048
#define BATCH 16
#define EMBD 256
#define HID 512
#define NG 1536            // 3*HID
#define NVOCAB 256
#define MROWS (TSEQ*BATCH) // 32768

typedef __attribute__((ext_vector_type(8))) unsigned short u16x8;
typedef __attribute__((ext_vector_type(8))) short s16x8;
typedef __attribute__((ext_vector_type(4))) float f32x4;

__device__ __forceinline__ float bf2f(unsigned short u) {
  union { unsigned u; float f; } x; x.u = ((unsigned)u) << 16; return x.f;
}
__device__ __forceinline__ unsigned short f2bf(float v) {
  union { float f; unsigned u; } x; x.f = v;
  unsigned r = (x.u + 0x7fffu + ((x.u >> 16) & 1u)) >> 16;
  return (unsigned short)r;
}
__device__ __forceinline__ float fast_rcp(float x) { return __builtin_amdgcn_rcpf(x); }
__device__ __forceinline__ float fast_sigmoid(float x) {
  float e = __builtin_amdgcn_exp2f(fminf(-1.442695041f * x, 80.f));
  return fast_rcp(1.f + e);
}
__device__ __forceinline__ float fast_tanh(float x) {
  float e = __builtin_amdgcn_exp2f(fminf(-2.885390082f * x, 80.f));
  return (1.f - e) * fast_rcp(1.f + e);
}
__device__ __forceinline__ void lds_cp16(const void* g, void* l) {
  __builtin_amdgcn_global_load_lds((const __attribute__((address_space(1))) void*)g,
                                   (__attribute__((address_space(3))) void*)l, 16, 0, 0);
}

// ---- embed: H0[m][e] bf16, m = t*16+b ----
__global__ __launch_bounds__(256) void embed_k(const int* __restrict__ x,
                                               const float* __restrict__ emb,
                                               unsigned short* __restrict__ H0) {
  int idx = blockIdx.x * 256 + threadIdx.x;   // 1M threads
  int m = idx >> 5, e8 = (idx & 31) * 8;
  int tok = x[(m & 15) * TSEQ + (m >> 4)];
  const float* e = emb + (size_t)tok * EMBD + e8;
  float4 v0 = *(const float4*)e;
  float4 v1 = *(const float4*)(e + 4);
  u16x8 o;
  o[0]=f2bf(v0.x); o[1]=f2bf(v0.y); o[2]=f2bf(v0.z); o[3]=f2bf(v0.w);
  o[4]=f2bf(v1.x); o[5]=f2bf(v1.y); o[6]=f2bf(v1.z); o[7]=f2bf(v1.w);
  *(u16x8*)(H0 + (size_t)m * EMBD + e8) = o;
}

// ---- weight transpose+convert: Wt[n][k] bf16 = W[k][n] f32 ----
__global__ __launch_bounds__(256) void wt_k(const float* __restrict__ W,
                                            unsigned short* __restrict__ Wt,
                                            int K, int N) {
  __shared__ float tile[32][33];
  int n0 = blockIdx.x * 32, k0 = blockIdx.y * 32;
  int tx = threadIdx.x, ty = threadIdx.y;
#pragma unroll
  for (int i = 0; i < 4; ++i)
    tile[ty + i * 8][tx] = W[(size_t)(k0 + ty + i * 8) * N + n0 + tx];
  __syncthreads();
#pragma unroll
  for (int i = 0; i < 4; ++i)
    Wt[(size_t)(n0 + ty + i * 8) * K + k0 + tx] = f2bf(tile[tx][ty + i * 8]);
}

// ---- MFMA GEMM: D[m][n] = A[m][k] @ Wt[n][k]^T  (both bf16, k-contiguous) ----
// BM=BN=128, BK=32, 256 thr = 4 waves (2x2 of 64x64), 16 MFMA/K-step.
// Core identical to the twice-passing round-4/5 version.
// EPI=0: gates -> act -> Y[m][1536] bf16 (coalesced via LDS re-tile)
// EPI=1: decoder -> f32 permuted store to out (B,T,V)
template <int K, int EPI>
__global__ __launch_bounds__(256) void gemm_k(const unsigned short* __restrict__ A,
                                              const unsigned short* __restrict__ Bt,
                                              const float* __restrict__ bias,
                                              unsigned short* __restrict__ Yg,
                                              float* __restrict__ Out) {
  __shared__ unsigned short smem[16384];  // 32 KB: staging A[0,4096) B[4096,8192); epilogue all
  unsigned short* sA = smem;
  unsigned short* sB = smem + 4096;
  const int tid = threadIdx.x;
  const int m0 = blockIdx.y * 128;
  const int n0 = blockIdx.x * 128;
  const int lane = tid & 63, wave = tid >> 6;
  const int wm = (wave >> 1) * 64, wn = (wave & 1) * 64;
  const int l15 = lane & 15, lg = lane >> 4;

  f32x4 acc[4][4] = {};

  for (int k0 = 0; k0 < K; k0 += 32) {
    // stage: 2 A + 2 B global_load_lds(16B) per thread; source pre-unswizzled
#pragma unroll
    for (int j = 0; j < 2; ++j) {
      int fl = j * 256 + tid;                       // 512 16-B chunks per tile
      int m = fl >> 2;
      int cl = ((fl & 3) << 4) ^ (((m >> 1) & 3) << 4);   // logical byte-col
      lds_cp16(A + (size_t)(m0 + m) * K + k0 + (cl >> 1), &sA[fl * 8]);
      lds_cp16(Bt + (size_t)(n0 + m) * K + k0 + (cl >> 1), &sB[fl * 8]);
    }
    __syncthreads();   // drains vmcnt(0) before barrier

    s16x8 af[4], bf[4];
#pragma unroll
    for (int i = 0; i < 4; ++i) {
      int ma = wm + i * 16 + l15;
      int ca = (lg * 16) ^ (((ma >> 1) & 3) << 4);
      af[i] = *(const s16x8*)&sA[ma * 32 + (ca >> 1)];
      int nb = wn + i * 16 + l15;
      int cb = (lg * 16) ^ (((nb >> 1) & 3) << 4);
      bf[i] = *(const s16x8*)&sB[nb * 32 + (cb >> 1)];
    }
#pragma unroll
    for (int i = 0; i < 4; ++i)
#pragma unroll
      for (int j = 0; j < 4; ++j)
        acc[i][j] = __builtin_amdgcn_mfma_f32_16x16x32_bf16(af[i], bf[j], acc[i][j], 0, 0, 0);
    __syncthreads();
  }

  if (EPI == 0) {
    // epilogue: bias + activation, LDS re-tile, coalesced store Y[m][n] bf16
    const int acttype = n0 >> 9;  // 0: z->tanh, 1/2: f,o->sigmoid
#pragma unroll
    for (int i = 0; i < 4; ++i)
#pragma unroll
      for (int j = 0; j < 4; ++j)
#pragma unroll
        for (int r = 0; r < 4; ++r) {
          int mm = wm + i * 16 + lg * 4 + r;   // C/D: row=(lane>>4)*4+reg (m89)
          int nn = wn + j * 16 + l15;          //      col=lane&15
          float v = acc[i][j][r] + bias[n0 + nn];
          v = (acttype == 0) ? fast_tanh(v) : fast_sigmoid(v);
          smem[mm * 128 + (nn ^ ((mm & 7) << 3))] = f2bf(v);
        }
    __syncthreads();
#pragma unroll
    for (int it = 0; it < 8; ++it) {
      int fl = it * 256 + tid;                 // 2048 16-B chunks
      int mm = fl >> 4, ng = (fl & 15) * 8;
      u16x8 v = *(const u16x8*)&smem[mm * 128 + (ng ^ ((mm & 7) << 3))];
      *(u16x8*)(Yg + (size_t)(m0 + mm) * NG + n0 + ng) = v;
    }
  } else {
    // decoder epilogue: f32 permuted store out[b][t][v]
#pragma unroll
    for (int i = 0; i < 4; ++i)
#pragma unroll
      for (int j = 0; j < 4; ++j)
#pragma unroll
        for (int r = 0; r < 4; ++r) {
          int mmg = m0 + wm + i * 16 + lg * 4 + r;
          int nn = n0 + wn + j * 16 + l15;
          float v = acc[i][j][r] + bias[nn];
          int b = mmg & 15, t = mmg >> 4;
          Out[((size_t)b * TSEQ + t) * NVOCAB + nn] = v;
        }
  }
}

// ---- segment-parallel fo-pool scan, full sequence (no chunking, no carry state) ----
// Chain (s,h): rows m = j*S + s of Y[m][1536], j in [0, 32768/S); gates z@h, f@512+h,
// o@1024+h (already activated). Block = 16 segments x 16 h for one s; segment length
// 2048>>LGS. Affine combine (c_out = A*c_in + B) in LDS, then rescan + write H.
template <int LGS>
__global__ __launch_bounds__(256) void scan3_k(const unsigned short* __restrict__ Y,
                                               unsigned short* __restrict__ Hout) {
  const int S = 1 << LGS;
  const int SEGLEN = 2048 >> LGS;     // 32768/(16*S)
  __shared__ float As[256], Bs[256], Ci[256];
  const int tid = threadIdx.x;
  const int hi = tid & 15, seg = tid >> 4;
  const int s = blockIdx.x >> 5, hg = blockIdx.x & 31;   // grid = S*32 blocks
  const int h = hg * 16 + hi;
  const long rbase = (long)s + (long)seg * SEGLEN * S;
  const size_t step = (size_t)S * NG;

  // phase A: per-segment affine (a = prod f, b = local scan from 0)
  float a = 1.f, c = 0.f;
  {
    const unsigned short* p = Y + (size_t)rbase * NG + h;
#pragma unroll 8
    for (int t = 0; t < SEGLEN; ++t) {
      float z = bf2f(p[0]);
      float f = bf2f(p[512]);
      a *= f;
      c = __builtin_fmaf(f, c - z, z);
      p += step;
    }
  }
  As[tid] = a;
  Bs[tid] = c;
  __syncthreads();

  // phase B: serial combine over 16 segments (16 lanes active, 16 iters)
  if (seg == 0) {
    float cc = 0.f;
#pragma unroll
    for (int k = 0; k < 16; ++k) {
      Ci[k * 16 + hi] = cc;
      cc = __builtin_fmaf(As[k * 16 + hi], cc, Bs[k * 16 + hi]);
    }
  }
  __syncthreads();

  // phase C: rescan with carry-in, write H (coalesced 32-B chunks in h)
  c = Ci[tid];
  const unsigned short* p = Y + (size_t)rbase * NG + h;
  unsigned short* hb = Hout + (size_t)rbase * HID + h;
  const size_t stepH = (size_t)S * HID;
#pragma unroll 4
  for (int t = 0; t < SEGLEN; ++t) {
    float z = bf2f(p[0]);
    float f = bf2f(p[512]);
    float o = bf2f(p[1024]);
    c = __builtin_fmaf(f, c - z, z);
    *hb = f2bf(o * c);
    p += step;
    hb += stepH;
  }
}

extern "C" void kernel_launch(void* const* d_in, const int* in_sizes, int n_in,
                              void* d_out, int out_size, void* d_ws, size_t ws_size,
                              hipStream_t stream) {
  const int* x = (const int*)d_in[0];
  const float* emb = (const float*)d_in[1];
  const float* Wl[4] = {(const float*)d_in[2], (const float*)d_in[4],
                        (const float*)d_in[6], (const float*)d_in[8]};
  const float* bl[4] = {(const float*)d_in[3], (const float*)d_in[5],
                        (const float*)d_in[7], (const float*)d_in[9]};
  const float* decW = (const float*)d_in[10];
  const float* decb = (const float*)d_in[11];
  float* out = (float*)d_out;

  // ws layout, total 139,984,896 B (~133.5 MB). Evidence from round-5 fills: ws_size = 256 MiB.
  if (ws_size < 139984896ull) return;   // diagnostic guard (clean zero-output if wrong)
  char* ws = (char*)d_ws;
  unsigned short* Y   = (unsigned short*)(ws);                         // 32768*1536*2 = 96 MB
  unsigned short* Ha  = (unsigned short*)(ws + 100663296ull);          // 32768*512*2 = 32 MB
  unsigned short* Wt0 = (unsigned short*)(ws + 134217728ull);          // 1536*256*2
  unsigned short* Wt1 = (unsigned short*)(ws + 135004160ull);          // 1536*512*2
  unsigned short* Wt2 = (unsigned short*)(ws + 136577024ull);
  unsigned short* Wt3 = (unsigned short*)(ws + 138149888ull);
  unsigned short* WtD = (unsigned short*)(ws + 139722752ull);          // 256*512*2
  unsigned short* Hb  = (unsigned short*)d_out;                        // scratch until decoder

  // weights: transpose+convert to bf16 [n][k]
  wt_k<<<dim3(NG / 32, EMBD / 32), dim3(32, 8), 0, stream>>>(Wl[0], Wt0, EMBD, NG);
  wt_k<<<dim3(NG / 32, HID / 32), dim3(32, 8), 0, stream>>>(Wl[1], Wt1, HID, NG);
  wt_k<<<dim3(NG / 32, HID / 32), dim3(32, 8), 0, stream>>>(Wl[2], Wt2, HID, NG);
  wt_k<<<dim3(NG / 32, HID / 32), dim3(32, 8), 0, stream>>>(Wl[3], Wt3, HID, NG);
  wt_k<<<dim3(NVOCAB / 32, HID / 32), dim3(32, 8), 0, stream>>>(decW, WtD, HID, NVOCAB);

  // embedding -> Ha [32768][256] bf16
  embed_k<<<(MROWS * (EMBD / 8)) / 256, 256, 0, stream>>>(x, emb, Ha);

  // layer 0: Ha -> Y -> Hb
  gemm_k<EMBD, 0><<<dim3(NG / 128, MROWS / 128), 256, 0, stream>>>(Ha, Wt0, bl[0], Y, nullptr);
  scan3_k<4><<<16 * 32, 256, 0, stream>>>(Y, Hb);
  // layer 1: Hb -> Y -> Ha
  gemm_k<HID, 0><<<dim3(NG / 128, MROWS / 128), 256, 0, stream>>>(Hb, Wt1, bl[1], Y, nullptr);
  scan3_k<5><<<32 * 32, 256, 0, stream>>>(Y, Ha);
  // layer 2: Ha -> Y -> Hb
  gemm_k<HID, 0><<<dim3(NG / 128, MROWS / 128), 256, 0, stream>>>(Ha, Wt2, bl[2], Y, nullptr);
  scan3_k<6><<<64 * 32, 256, 0, stream>>>(Y, Hb);
  // layer 3: Hb -> Y -> Ha
  gemm_k<HID, 0><<<dim3(NG / 128, MROWS / 128), 256, 0, stream>>>(Hb, Wt3, bl[3], Y, nullptr);
  scan3_k<7><<<128 * 32, 256, 0, stream>>>(Y, Ha);

  // decoder: out[b][t][v] = Ha @ decW + decb
  gemm_k<HID, 1><<<dim3(NVOCAB / 128, MROWS / 128), 256, 0, stream>>>(Ha, WtD, decb, nullptr, out);
}

// Round 7
// 780.986 us; speedup vs baseline: 1.1378x; 1.1378x over previous
//
#include <hip/hip_runtime.h>

#define TSEQ 2048
#define BATCH 16
#define EMBD 256
#define HID 512
#define NG 1536            // 3*HID
#define NVOCAB 256
#define MROWS (TSEQ*BATCH) // 32768
#define CM 8192            // chunk rows (4 chunks)

typedef __attribute__((ext_vector_type(8))) unsigned short u16x8;
typedef __attribute__((ext_vector_type(8))) short s16x8;
typedef __attribute__((ext_vector_type(4))) float f32x4;

__device__ __forceinline__ float bf2f(unsigned short u) {
  union { unsigned u; float f; } x; x.u = ((unsigned)u) << 16; return x.f;
}
__device__ __forceinline__ unsigned short f2bf(float v) {
  union { float f; unsigned u; } x; x.f = v;
  unsigned r = (x.u + 0x7fffu + ((x.u >> 16) & 1u)) >> 16;
  return (unsigned short)r;
}
__device__ __forceinline__ float fast_rcp(float x) { return __builtin_amdgcn_rcpf(x); }
__device__ __forceinline__ float fast_sigmoid(float x) {
  float e = __builtin_amdgcn_exp2f(fminf(-1.442695041f * x, 80.f));
  return fast_rcp(1.f + e);
}
__device__ __forceinline__ float fast_tanh(float x) {
  float e = __builtin_amdgcn_exp2f(fminf(-2.885390082f * x, 80.f));
  return (1.f - e) * fast_rcp(1.f + e);
}
__device__ __forceinline__ void lds_cp16(const void* g, void* l) {
  __builtin_amdgcn_global_load_lds((const __attribute__((address_space(1))) void*)g,
                                   (__attribute__((address_space(3))) void*)l, 16, 0, 0);
}

// ---- embed: H0[m][e] bf16, m = t*16+b ----
__global__ __launch_bounds__(256) void embed_k(const int* __restrict__ x,
                                               const float* __restrict__ emb,
                                               unsigned short* __restrict__ H0) {
  int idx = blockIdx.x * 256 + threadIdx.x;   // 1M threads
  int m = idx >> 5, e8 = (idx & 31) * 8;
  int tok = x[(m & 15) * TSEQ + (m >> 4)];
  const float* e = emb + (size_t)tok * EMBD + e8;
  float4 v0 = *(const float4*)e;
  float4 v1 = *(const float4*)(e + 4);
  u16x8 o;
  o[0]=f2bf(v0.x); o[1]=f2bf(v0.y); o[2]=f2bf(v0.z); o[3]=f2bf(v0.w);
  o[4]=f2bf(v1.x); o[5]=f2bf(v1.y); o[6]=f2bf(v1.z); o[7]=f2bf(v1.w);
  *(u16x8*)(H0 + (size_t)m * EMBD + e8) = o;
}

// ---- weight transpose+convert: Wt[n][k] bf16 = W[k][n] f32 ----
__global__ __launch_bounds__(256) void wt_k(const float* __restrict__ W,
                                            unsigned short* __restrict__ Wt,
                                            int K, int N) {
  __shared__ float tile[32][33];
  int n0 = blockIdx.x * 32, k0 = blockIdx.y * 32;
  int tx = threadIdx.x, ty = threadIdx.y;
#pragma unroll
  for (int i = 0; i < 4; ++i)
    tile[ty + i * 8][tx] = W[(size_t)(k0 + ty + i * 8) * N + n0 + tx];
  __syncthreads();
#pragma unroll
  for (int i = 0; i < 4; ++i)
    Wt[(size_t)(n0 + ty + i * 8) * K + k0 + tx] = f2bf(tile[tx][ty + i * 8]);
}

// ---- MFMA GEMM: D[m][n] = A[m][k] @ Wt[n][k]^T  (both bf16, k-contiguous) ----
// BM=BN=128, BK=64, 256 thr = 4 waves (2x2 of 64x64), 32 MFMA/K-step, 2 barriers/K-step.
// LDS rows 128B, XOR swizzle byte ^= (row&7)<<4 (both-sides involution) ->
// conflict-free ds_read_b128 fragments. Accumulation order identical to BK=32 version.
// EPI=0: gates -> act -> Y[m][1536] bf16 (coalesced via LDS re-tile)
// EPI=1: decoder -> f32 permuted store to out (B,T,V)
template <int K, int EPI>
__global__ __launch_bounds__(256) void gemm_k(const unsigned short* __restrict__ A,
                                              const unsigned short* __restrict__ Bt,
                                              const float* __restrict__ bias,
                                              unsigned short* __restrict__ Yg,
                                              float* __restrict__ Out) {
  __shared__ unsigned short smem[16384];  // 32 KB: staging A[0,8192) B[8192,16384); epilogue all
  unsigned short* sA = smem;
  unsigned short* sB = smem + 8192;
  const int tid = threadIdx.x;
  const int m0 = blockIdx.y * 128;
  const int n0 = blockIdx.x * 128;
  const int lane = tid & 63, wave = tid >> 6;
  const int wm = (wave >> 1) * 64, wn = (wave & 1) * 64;
  const int l15 = lane & 15, lg = lane >> 4;

  f32x4 acc[4][4] = {};

  for (int k0 = 0; k0 < K; k0 += 64) {
    // stage 128x64 A and B tiles: 4 A + 4 B global_load_lds(16B) per thread.
    // LDS phys row = 128B; chunk fl -> row m=fl>>3, phys byte (fl&7)*16,
    // logical byte col cl = phys ^ ((m&7)<<4)  (source pre-unswizzled)
#pragma unroll
    for (int j = 0; j < 4; ++j) {
      int fl = j * 256 + tid;                       // 1024 16-B chunks per tile
      int m = fl >> 3;
      int cl = ((fl & 7) << 4) ^ ((m & 7) << 4);
      lds_cp16(A + (size_t)(m0 + m) * K + k0 + (cl >> 1), &sA[fl * 8]);
      lds_cp16(Bt + (size_t)(n0 + m) * K + k0 + (cl >> 1), &sB[fl * 8]);
    }
    __syncthreads();   // drains vmcnt(0) before barrier

#pragma unroll
    for (int kk = 0; kk < 2; ++kk) {               // two k=32 sub-steps
      s16x8 af[4], bf[4];
#pragma unroll
      for (int i = 0; i < 4; ++i) {
        int ma = wm + i * 16 + l15;
        int ca = (kk * 64 + lg * 16) ^ ((ma & 7) << 4);
        af[i] = *(const s16x8*)&sA[ma * 64 + (ca >> 1)];
        int nb = wn + i * 16 + l15;
        int cb = (kk * 64 + lg * 16) ^ ((nb & 7) << 4);
        bf[i] = *(const s16x8*)&sB[nb * 64 + (cb >> 1)];
      }
#pragma unroll
      for (int i = 0; i < 4; ++i)
#pragma unroll
        for (int j = 0; j < 4; ++j)
          acc[i][j] = __builtin_amdgcn_mfma_f32_16x16x32_bf16(af[i], bf[j], acc[i][j], 0, 0, 0);
    }
    __syncthreads();
  }

  if (EPI == 0) {
    // epilogue: bias + activation, LDS re-tile, coalesced store Y[m][n] bf16
    const int acttype = n0 >> 9;  // 0: z->tanh, 1/2: f,o->sigmoid
#pragma unroll
    for (int i = 0; i < 4; ++i)
#pragma unroll
      for (int j = 0; j < 4; ++j)
#pragma unroll
        for (int r = 0; r < 4; ++r) {
          int mm = wm + i * 16 + lg * 4 + r;   // C/D: row=(lane>>4)*4+reg (m89)
          int nn = wn + j * 16 + l15;          //      col=lane&15
          float v = acc[i][j][r] + bias[n0 + nn];
          v = (acttype == 0) ? fast_tanh(v) : fast_sigmoid(v);
          smem[mm * 128 + (nn ^ ((mm & 7) << 3))] = f2bf(v);
        }
    __syncthreads();
#pragma unroll
    for (int it = 0; it < 8; ++it) {
      int fl = it * 256 + tid;                 // 2048 16-B chunks
      int mm = fl >> 4, ng = (fl & 15) * 8;
      u16x8 v = *(const u16x8*)&smem[mm * 128 + (ng ^ ((mm & 7) << 3))];
      *(u16x8*)(Yg + (size_t)(m0 + mm) * NG + n0 + ng) = v;
    }
  } else {
    // decoder epilogue: f32 permuted store out[b][t][v]
#pragma unroll
    for (int i = 0; i < 4; ++i)
#pragma unroll
      for (int j = 0; j < 4; ++j)
#pragma unroll
        for (int r = 0; r < 4; ++r) {
          int mmg = m0 + wm + i * 16 + lg * 4 + r;
          int nn = n0 + wn + j * 16 + l15;
          float v = acc[i][j][r] + bias[nn];
          int b = mmg & 15, t = mmg >> 4;
          Out[((size_t)b * TSEQ + t) * NVOCAB + nn] = v;
        }
  }
}

// ---- segment-parallel fo-pool scan, fused 3-phase, one kernel per chunk ----
// (verbatim round-5 version — proven with chunked, cache-resident Y)
template <int LGS>
__global__ __launch_bounds__(256) void scan2_k(const unsigned short* __restrict__ Y,
                                               unsigned short* __restrict__ Hout,
                                               float* __restrict__ cst,
                                               int m0, int init) {
  const int S = 1 << LGS;            // dilation slots
  const int HS = 1 << LGS;           // h-values per block
  const int NSEG = 1 << (8 - LGS);   // segments per chain (chain len = 32*NSEG = CM/S)
  __shared__ float As[256], Bs[256], Ci[256];   // [NSEG][HS]

  const int tid = threadIdx.x;
  const int hi = tid & (HS - 1), seg = tid >> LGS;
  const int hg = blockIdx.x & ((2 * NSEG) - 1);
  const int s = blockIdx.x >> (9 - LGS);
  const int h = hg * HS + hi;
  const int mb = seg * 32 * S + s;

  // phase A: per-segment affine transform (A = prod f, B = scan from 0)
  float a = 1.f, c = 0.f;
#pragma unroll 8
  for (int t = 0; t < 32; ++t) {
    size_t ro = (size_t)(mb + t * S) * NG;
    float z = bf2f(Y[ro + h]);
    float f = bf2f(Y[ro + 512 + h]);
    a *= f;
    c = __builtin_fmaf(f, c - z, z);
  }
  As[seg * HS + hi] = a;
  Bs[seg * HS + hi] = c;
  __syncthreads();

  // phase B: serial combine over segments (seg-0 threads), carry from/to cst
  if (seg == 0) {
    float cc = init ? 0.f : cst[s * 512 + h];
#pragma unroll
    for (int k = 0; k < NSEG; ++k) {
      Ci[k * HS + hi] = cc;
      cc = __builtin_fmaf(As[k * HS + hi], cc, Bs[k * HS + hi]);
    }
    cst[s * 512 + h] = cc;
  }
  __syncthreads();

  // phase C: rescan with correct carry-in, write H (coalesced in h)
  c = Ci[seg * HS + hi];
#pragma unroll 8
  for (int t = 0; t < 32; ++t) {
    size_t ro = (size_t)(mb + t * S) * NG;
    float z = bf2f(Y[ro + h]);
    float f = bf2f(Y[ro + 512 + h]);
    float o = bf2f(Y[ro + 1024 + h]);
    c = __builtin_fmaf(f, c - z, z);
    Hout[(size_t)(m0 + mb + t * S) * HID + h] = f2bf(o * c);
  }
}

extern "C" void kernel_launch(void* const* d_in, const int* in_sizes, int n_in,
                              void* d_out, int out_size, void* d_ws, size_t ws_size,
                              hipStream_t stream) {
  const int* x = (const int*)d_in[0];
  const float* emb = (const float*)d_in[1];
  const float* Wl[4] = {(const float*)d_in[2], (const float*)d_in[4],
                        (const float*)d_in[6], (const float*)d_in[8]};
  const float* bl[4] = {(const float*)d_in[3], (const float*)d_in[5],
                        (const float*)d_in[7], (const float*)d_in[9]};
  const float* decW = (const float*)d_in[10];
  const float* decb = (const float*)d_in[11];
  float* out = (float*)d_out;

  // ws layout: identical to proven-safe round-4/5 layout (64,749,568 B).
  if (ws_size < 64749568ull) return;
  char* ws = (char*)d_ws;
  unsigned short* Y   = (unsigned short*)(ws);                        // 8192*1536*2 = 24 MB
  unsigned short* Ha  = (unsigned short*)(ws + 25165824ull);          // 32768*512*2 = 32 MB
  unsigned short* Wt0 = (unsigned short*)(ws + 58720256ull);          // 1536*256*2
  unsigned short* Wt1 = (unsigned short*)(ws + 59506688ull);          // 1536*512*2
  unsigned short* Wt2 = (unsigned short*)(ws + 61079552ull);
  unsigned short* Wt3 = (unsigned short*)(ws + 62652416ull);
  unsigned short* WtD = (unsigned short*)(ws + 64225280ull);          // 256*512*2
  float*          cst = (float*)(ws + 64487424ull);                   // 65536*4 = 256 KB
  unsigned short* Hb  = (unsigned short*)d_out;                       // scratch until decoder

  // weights: transpose+convert to bf16 [n][k]
  wt_k<<<dim3(NG / 32, EMBD / 32), dim3(32, 8), 0, stream>>>(Wl[0], Wt0, EMBD, NG);
  wt_k<<<dim3(NG / 32, HID / 32), dim3(32, 8), 0, stream>>>(Wl[1], Wt1, HID, NG);
  wt_k<<<dim3(NG / 32, HID / 32), dim3(32, 8), 0, stream>>>(Wl[2], Wt2, HID, NG);
  wt_k<<<dim3(NG / 32, HID / 32), dim3(32, 8), 0, stream>>>(Wl[3], Wt3, HID, NG);
  wt_k<<<dim3(NVOCAB / 32, HID / 32), dim3(32, 8), 0, stream>>>(decW, WtD, HID, NVOCAB);

  // embedding -> Ha [32768][256] bf16
  embed_k<<<(MROWS * (EMBD / 8)) / 256, 256, 0, stream>>>(x, emb, Ha);

  unsigned short* Wts[4] = {Wt0, Wt1, Wt2, Wt3};
  unsigned short* Hbuf[2] = {Ha, Hb};
  for (int L = 0; L < 4; ++L) {
    unsigned short* Hin = Hbuf[L & 1];
    unsigned short* Hout = Hbuf[(L + 1) & 1];
    const int Kd = (L == 0) ? EMBD : HID;
    for (int ch = 0; ch < MROWS / CM; ++ch) {
      const unsigned short* Ach = Hin + (size_t)ch * CM * Kd;
      if (L == 0)
        gemm_k<EMBD, 0><<<dim3(NG / 128, CM / 128), 256, 0, stream>>>(Ach, Wts[L], bl[L], Y, nullptr);
      else
        gemm_k<HID, 0><<<dim3(NG / 128, CM / 128), 256, 0, stream>>>(Ach, Wts[L], bl[L], Y, nullptr);
      switch (L) {
        case 0: scan2_k<4><<<512, 256, 0, stream>>>(Y, Hout, cst, ch * CM, ch == 0); break;
        case 1: scan2_k<5><<<512, 256, 0, stream>>>(Y, Hout, cst, ch * CM, ch == 0); break;
        case 2: scan2_k<6><<<512, 256, 0, stream>>>(Y, Hout, cst, ch * CM, ch == 0); break;
        case 3: scan2_k<7><<<512, 256, 0, stream>>>(Y, Hout, cst, ch * CM, ch == 0); break;
      }
    }
  }

  // decoder: out[b][t][v] = Ha @ decW + decb
  gemm_k<HID, 1><<<dim3(NVOCAB / 128, MROWS / 128), 256, 0, stream>>>(Hbuf[0], WtD, decb, nullptr, out);
}

// Round 9
// 701.409 us; speedup vs baseline: 1.2669x; 1.1135x over previous
//
#include <hip/hip_runtime.h>

#define TSEQ 2048
#define BATCH 16
#define EMBD 256
#define HID 512
#define NG 1536            // 3*HID
#define NVOCAB 256
#define MROWS (TSEQ*BATCH) // 32768
#define CM 8192            // chunk rows (4 chunks)

typedef __attribute__((ext_vector_type(8))) unsigned short u16x8;
typedef __attribute__((ext_vector_type(8))) short s16x8;
typedef __attribute__((ext_vector_type(4))) float f32x4;

__device__ __forceinline__ float bf2f(unsigned short u) {
  union { unsigned u; float f; } x; x.u = ((unsigned)u) << 16; return x.f;
}
__device__ __forceinline__ unsigned short f2bf(float v) {
  union { float f; unsigned u; } x; x.f = v;
  unsigned r = (x.u + 0x7fffu + ((x.u >> 16) & 1u)) >> 16;
  return (unsigned short)r;
}
__device__ __forceinline__ float fast_rcp(float x) { return __builtin_amdgcn_rcpf(x); }
__device__ __forceinline__ float fast_sigmoid(float x) {
  float e = __builtin_amdgcn_exp2f(fminf(-1.442695041f * x, 80.f));
  return fast_rcp(1.f + e);
}
__device__ __forceinline__ float fast_tanh(float x) {
  float e = __builtin_amdgcn_exp2f(fminf(-2.885390082f * x, 80.f));
  return (1.f - e) * fast_rcp(1.f + e);
}
__device__ __forceinline__ void lds_cp16(const void* g, void* l) {
  __builtin_amdgcn_global_load_lds((const __attribute__((address_space(1))) void*)g,
                                   (__attribute__((address_space(3))) void*)l, 16, 0, 0);
}

// ---- embed: H0[m][e] bf16, m = t*16+b ----
__global__ __launch_bounds__(256) void embed_k(const int* __restrict__ x,
                                               const float* __restrict__ emb,
                                               unsigned short* __restrict__ H0) {
  int idx = blockIdx.x * 256 + threadIdx.x;   // 1M threads
  int m = idx >> 5, e8 = (idx & 31) * 8;
  int tok = x[(m & 15) * TSEQ + (m >> 4)];
  const float* e = emb + (size_t)tok * EMBD + e8;
  float4 v0 = *(const float4*)e;
  float4 v1 = *(const float4*)(e + 4);
  u16x8 o;
  o[0]=f2bf(v0.x); o[1]=f2bf(v0.y); o[2]=f2bf(v0.z); o[3]=f2bf(v0.w);
  o[4]=f2bf(v1.x); o[5]=f2bf(v1.y); o[6]=f2bf(v1.z); o[7]=f2bf(v1.w);
  *(u16x8*)(H0 + (size_t)m * EMBD + e8) = o;
}

// ---- weight transpose+convert: Wt[n][k] bf16 = W[k][n] f32 ----
__global__ __launch_bounds__(256) void wt_k(const float* __restrict__ W,
                                            unsigned short* __restrict__ Wt,
                                            int K, int N) {
  __shared__ float tile[32][33];
  int n0 = blockIdx.x * 32, k0 = blockIdx.y * 32;
  int tx = threadIdx.x, ty = threadIdx.y;
#pragma unroll
  for (int i = 0; i < 4; ++i)
    tile[ty + i * 8][tx] = W[(size_t)(k0 + ty + i * 8) * N + n0 + tx];
  __syncthreads();
#pragma unroll
  for (int i = 0; i < 4; ++i)
    Wt[(size_t)(n0 + ty + i * 8) * K + k0 + tx] = f2bf(tile[tx][ty + i * 8]);
}

// ---- MFMA GEMM: D[m][n] = A[m][k] @ Wt[n][k]^T  (both bf16, k-contiguous) ----
// BM=BN=128, BK=32, 256 thr = 4 waves (2x2 of 64x64), 16 MFMA/K-step.
// EXACT round-5 core (best-known: 709 us total). BK=64 variant regressed (+72 us) — do not re-try.
// EPI=0: gates -> act -> Y[m][1536] bf16 (coalesced via LDS re-tile)
// EPI=1: decoder -> f32 permuted store to out (B,T,V)
template <int K, int EPI>
__global__ __launch_bounds__(256) void gemm_k(const unsigned short* __restrict__ A,
                                              const unsigned short* __restrict__ Bt,
                                              const float* __restrict__ bias,
                                              unsigned short* __restrict__ Yg,
                                              float* __restrict__ Out) {
  __shared__ unsigned short smem[16384];  // 32 KB: staging A[0,4096) B[4096,8192); epilogue all
  unsigned short* sA = smem;
  unsigned short* sB = smem + 4096;
  const int tid = threadIdx.x;
  const int m0 = blockIdx.y * 128;
  const int n0 = blockIdx.x * 128;
  const int lane = tid & 63, wave = tid >> 6;
  const int wm = (wave >> 1) * 64, wn = (wave & 1) * 64;
  const int l15 = lane & 15, lg = lane >> 4;

  f32x4 acc[4][4] = {};

  for (int k0 = 0; k0 < K; k0 += 32) {
    // stage: 2 A + 2 B global_load_lds(16B) per thread; source pre-unswizzled
#pragma unroll
    for (int j = 0; j < 2; ++j) {
      int fl = j * 256 + tid;                       // 512 16-B chunks per tile
      int m = fl >> 2;
      int cl = ((fl & 3) << 4) ^ (((m >> 1) & 3) << 4);   // logical byte-col
      lds_cp16(A + (size_t)(m0 + m) * K + k0 + (cl >> 1), &sA[fl * 8]);
      lds_cp16(Bt + (size_t)(n0 + m) * K + k0 + (cl >> 1), &sB[fl * 8]);
    }
    __syncthreads();   // drains vmcnt(0) before barrier

    s16x8 af[4], bf[4];
#pragma unroll
    for (int i = 0; i < 4; ++i) {
      int ma = wm + i * 16 + l15;
      int ca = (lg * 16) ^ (((ma >> 1) & 3) << 4);
      af[i] = *(const s16x8*)&sA[ma * 32 + (ca >> 1)];
      int nb = wn + i * 16 + l15;
      int cb = (lg * 16) ^ (((nb >> 1) & 3) << 4);
      bf[i] = *(const s16x8*)&sB[nb * 32 + (cb >> 1)];
    }
#pragma unroll
    for (int i = 0; i < 4; ++i)
#pragma unroll
      for (int j = 0; j < 4; ++j)
        acc[i][j] = __builtin_amdgcn_mfma_f32_16x16x32_bf16(af[i], bf[j], acc[i][j], 0, 0, 0);
    __syncthreads();
  }

  if (EPI == 0) {
    // epilogue: bias + activation, LDS re-tile, coalesced store Y[m][n] bf16
    const int acttype = n0 >> 9;  // 0: z->tanh, 1/2: f,o->sigmoid
#pragma unroll
    for (int i = 0; i < 4; ++i)
#pragma unroll
      for (int j = 0; j < 4; ++j)
#pragma unroll
        for (int r = 0; r < 4; ++r) {
          int mm = wm + i * 16 + lg * 4 + r;   // C/D: row=(lane>>4)*4+reg (m89)
          int nn = wn + j * 16 + l15;          //      col=lane&15
          float v = acc[i][j][r] + bias[n0 + nn];
          v = (acttype == 0) ? fast_tanh(v) : fast_sigmoid(v);
          smem[mm * 128 + (nn ^ ((mm & 7) << 3))] = f2bf(v);
        }
    __syncthreads();
#pragma unroll
    for (int it = 0; it < 8; ++it) {
      int fl = it * 256 + tid;                 // 2048 16-B chunks
      int mm = fl >> 4, ng = (fl & 15) * 8;
      u16x8 v = *(const u16x8*)&smem[mm * 128 + (ng ^ ((mm & 7) << 3))];
      *(u16x8*)(Yg + (size_t)(m0 + mm) * NG + n0 + ng) = v;
    }
  } else {
    // decoder epilogue: f32 permuted store out[b][t][v]
#pragma unroll
    for (int i = 0; i < 4; ++i)
#pragma unroll
      for (int j = 0; j < 4; ++j)
#pragma unroll
        for (int r = 0; r < 4; ++r) {
          int mmg = m0 + wm + i * 16 + lg * 4 + r;
          int nn = n0 + wn + j * 16 + l15;
          float v = acc[i][j][r] + bias[nn];
          int b = mmg & 15, t = mmg >> 4;
          Out[((size_t)b * TSEQ + t) * NVOCAB + nn] = v;
        }
  }
}

// ---- segment-parallel fo-pool scan, fused 3-phase, one kernel per chunk ----
// WIDENED vs round 5: block = 8 segments x 32 h-values -> each 32-lane group reads
// 64 B contiguous (full cache lines; was 32 B = 2x over-fetch on misses).
// Chain (s,h): rows m = t*S + s of Y[m][1536]; z@h, f@512+h, o@1024+h (activated).
// Affine combine c_out = A*c_in + B in LDS; cross-chunk carry in cst[s*512+h].
template <int LGS>
__global__ __launch_bounds__(256) void scan2_k(const unsigned short* __restrict__ Y,
                                               unsigned short* __restrict__ Hout,
                                               float* __restrict__ cst,
                                               int m0, int init) {
  const int S = 1 << LGS;            // dilation slots
  const int SEGLEN = 1024 >> LGS;    // CM/(S*8)
  __shared__ float As[256], Bs[256], Ci[256];   // [8 seg][32 h]

  const int tid = threadIdx.x;
  const int hi = tid & 31, seg = tid >> 5;
  const int s = blockIdx.x >> 4, hg = blockIdx.x & 15;   // grid = S*16 blocks
  const int h = hg * 32 + hi;
  const int mb = seg * SEGLEN * S + s;
  const size_t step = (size_t)S * NG;

  // phase A: per-segment affine (a = prod f, b = local scan from 0)
  float a = 1.f, c = 0.f;
  {
    const unsigned short* p = Y + (size_t)mb * NG + h;
#pragma unroll 8
    for (int t = 0; t < SEGLEN; ++t) {
      float z = bf2f(p[0]);
      float f = bf2f(p[512]);
      a *= f;
      c = __builtin_fmaf(f, c - z, z);
      p += step;
    }
  }
  As[tid] = a;
  Bs[tid] = c;
  __syncthreads();

  // phase B: serial combine over 8 segments (32 lanes active), carry from/to cst
  if (seg == 0) {
    float cc = init ? 0.f : cst[s * 512 + h];
#pragma unroll
    for (int k = 0; k < 8; ++k) {
      Ci[k * 32 + hi] = cc;
      cc = __builtin_fmaf(As[k * 32 + hi], cc, Bs[k * 32 + hi]);
    }
    cst[s * 512 + h] = cc;
  }
  __syncthreads();

  // phase C: rescan with correct carry-in, write H (coalesced 64-B chunks in h)
  c = Ci[tid];
  const unsigned short* p = Y + (size_t)mb * NG + h;
  unsigned short* hb = Hout + (size_t)(m0 + mb) * HID + h;
  const size_t stepH = (size_t)S * HID;
#pragma unroll 4
  for (int t = 0; t < SEGLEN; ++t) {
    float z = bf2f(p[0]);
    float f = bf2f(p[512]);
    float o = bf2f(p[1024]);
    c = __builtin_fmaf(f, c - z, z);
    *hb = f2bf(o * c);
    p += step;
    hb += stepH;
  }
}

extern "C" void kernel_launch(void* const* d_in, const int* in_sizes, int n_in,
                              void* d_out, int out_size, void* d_ws, size_t ws_size,
                              hipStream_t stream) {
  const int* x = (const int*)d_in[0];
  const float* emb = (const float*)d_in[1];
  const float* Wl[4] = {(const float*)d_in[2], (const float*)d_in[4],
                        (const float*)d_in[6], (const float*)d_in[8]};
  const float* bl[4] = {(const float*)d_in[3], (const float*)d_in[5],
                        (const float*)d_in[7], (const float*)d_in[9]};
  const float* decW = (const float*)d_in[10];
  const float* decb = (const float*)d_in[11];
  float* out = (float*)d_out;

  // ws layout: identical to proven-safe round-4/5 layout (64,749,568 B).
  if (ws_size < 64749568ull) return;
  char* ws = (char*)d_ws;
  unsigned short* Y   = (unsigned short*)(ws);                        // 8192*1536*2 = 24 MB
  unsigned short* Ha  = (unsigned short*)(ws + 25165824ull);          // 32768*512*2 = 32 MB
  unsigned short* Wt0 = (unsigned short*)(ws + 58720256ull);          // 1536*256*2
  unsigned short* Wt1 = (unsigned short*)(ws + 59506688ull);          // 1536*512*2
  unsigned short* Wt2 = (unsigned short*)(ws + 61079552ull);
  unsigned short* Wt3 = (unsigned short*)(ws + 62652416ull);
  unsigned short* WtD = (unsigned short*)(ws + 64225280ull);          // 256*512*2
  float*          cst = (float*)(ws + 64487424ull);                   // 65536*4 = 256 KB
  unsigned short* Hb  = (unsigned short*)d_out;                       // scratch until decoder

  // weights: transpose+convert to bf16 [n][k]
  wt_k<<<dim3(NG / 32, EMBD / 32), dim3(32, 8), 0, stream>>>(Wl[0], Wt0, EMBD, NG);
  wt_k<<<dim3(NG / 32, HID / 32), dim3(32, 8), 0, stream>>>(Wl[1], Wt1, HID, NG);
  wt_k<<<dim3(NG / 32, HID / 32), dim3(32, 8), 0, stream>>>(Wl[2], Wt2, HID, NG);
  wt_k<<<dim3(NG / 32, HID / 32), dim3(32, 8), 0, stream>>>(Wl[3], Wt3, HID, NG);
  wt_k<<<dim3(NVOCAB / 32, HID / 32), dim3(32, 8), 0, stream>>>(decW, WtD, HID, NVOCAB);

  // embedding -> Ha [32768][256] bf16
  embed_k<<<(MROWS * (EMBD / 8)) / 256, 256, 0, stream>>>(x, emb, Ha);

  unsigned short* Wts[4] = {Wt0, Wt1, Wt2, Wt3};
  unsigned short* Hbuf[2] = {Ha, Hb};
  for (int L = 0; L < 4; ++L) {
    unsigned short* Hin = Hbuf[L & 1];
    unsigned short* Hout = Hbuf[(L + 1) & 1];
    const int Kd = (L == 0) ? EMBD : HID;
    for (int ch = 0; ch < MROWS / CM; ++ch) {
      const unsigned short* Ach = Hin + (size_t)ch * CM * Kd;
      if (L == 0)
        gemm_k<EMBD, 0><<<dim3(NG / 128, CM / 128), 256, 0, stream>>>(Ach, Wts[L], bl[L], Y, nullptr);
      else
        gemm_k<HID, 0><<<dim3(NG / 128, CM / 128), 256, 0, stream>>>(Ach, Wts[L], bl[L], Y, nullptr);
      switch (L) {
        case 0: scan2_k<4><<<16 * 16, 256, 0, stream>>>(Y, Hout, cst, ch * CM, ch == 0); break;
        case 1: scan2_k<5><<<32 * 16, 256, 0, stream>>>(Y, Hout, cst, ch * CM, ch == 0); break;
        case 2: scan2_k<6><<<64 * 16, 256, 0, stream>>>(Y, Hout, cst, ch * CM, ch == 0); break;
        case 3: scan2_k<7><<<128 * 16, 256, 0, stream>>>(Y, Hout, cst, ch * CM, ch == 0); break;
      }
    }
  }

  // decoder: out[b][t][v] = Ha @ decW + decb
  gemm_k<HID, 1><<<dim3(NVOCAB / 128, MROWS / 128), 256, 0, stream>>>(Hbuf[0], WtD, decb, nullptr, out);
}